// Round 11
// baseline (6621.609 us; speedup 1.0000x reference)
//
#include <hip/hip_runtime.h>
#include <cstdint>
#include <cstddef>

#define DEPTH 100
#define HID 1024
#define MROWS 4096
#define NSTEPS 202

typedef _Float16 half8 __attribute__((ext_vector_type(8)));
typedef float floatx4 __attribute__((ext_vector_type(4)));

__device__ __forceinline__ void gload_lds16_a(const void* g, void* l) {
    __builtin_amdgcn_global_load_lds((const __attribute__((address_space(1))) void*)g,
                                     (__attribute__((address_space(3))) void*)l, 16, 0, 1);
}
__device__ __forceinline__ void gload_lds16_w(const void* g, void* l) {
    __builtin_amdgcn_global_load_lds((const __attribute__((address_space(1))) void*)g,
                                     (__attribute__((address_space(3))) void*)l, 16, 0, 2);
}
__device__ __forceinline__ float ld_sc0_f32(const float* p) {
    return __hip_atomic_load(p, __ATOMIC_RELAXED, __HIP_MEMORY_SCOPE_AGENT);
}

// ============================================================================
// R11 = R9 (proven: 256 blocks x 512 thr, 163840B LDS, 1 blk/CU, Ht-in-LDS,
// strips, 3-deep counted-vmcnt K-loop) with ONE change: the per-step 32-block
// XCD barrier is replaced by per-(bm,step) 8-arrival DATAFLOW FLAGS.
// Row-group (bm,*) chains are fully independent (rb/ab rows + strips are all
// row-panel-local), so groups slip freely -> no whole-XCD straggler convoy.
// Weight staging (no dependency) is issued BEFORE the flag spin, hiding HBM
// weight latency under the wait; first k-tile gate becomes vmcnt(6).
// Fallback (okf=0): R4-proven global fenced barrier, unchanged.
// ============================================================================
__global__ __launch_bounds__(512, 1)
void resnet_persist(const _Float16* __restrict__ xh, const _Float16* __restrict__ fc1h,
                    const float* __restrict__ fc1_b,
                    const _Float16* __restrict__ W1h, const float* __restrict__ b1,
                    const _Float16* __restrict__ W2h, const float* __restrict__ b2,
                    const _Float16* __restrict__ fc2h, const float* __restrict__ fc2_b,
                    float* __restrict__ Sst, _Float16* __restrict__ rb,
                    _Float16* __restrict__ ab, float* __restrict__ outp,
                    unsigned* __restrict__ ctr)
{
    __shared__ _Float16 As[3][128 * 64];   // 48 KB
    __shared__ _Float16 Bs[3][128 * 64];   // 48 KB
    __shared__ float    Ht[128 * 128];     // 64 KB persistent h tile

    const int tid = threadIdx.x;
    const int l   = tid & 63;
    const int w   = tid >> 6;        // wave 0..7
    const int wm  = w >> 2;          // 0..1 along M
    const int wn  = w & 3;           // 0..3 along N

    const int lr = l >> 3;
    const int lj = l & 7;
    const int sw = (l & 7) << 4;

    // ---- registration ----
    unsigned xcd_s;
    asm volatile("s_getreg_b32 %0, hwreg(HW_REG_XCC_ID)" : "=s"(xcd_s));
    unsigned* shm = (unsigned*)Ht;
    if (tid == 0) {
        const unsigned x = xcd_s & 7u;
        const unsigned r = __hip_atomic_fetch_add(&ctr[x * 32], 1u, __ATOMIC_RELAXED, __HIP_MEMORY_SCOPE_AGENT);
        __hip_atomic_fetch_add(&ctr[8 * 32], 1u, __ATOMIC_RELEASE, __HIP_MEMORY_SCOPE_AGENT);
        while (__hip_atomic_load(&ctr[8 * 32], __ATOMIC_RELAXED, __HIP_MEMORY_SCOPE_AGENT) < 256u)
            __builtin_amdgcn_s_sleep(2);
        __builtin_amdgcn_fence(__ATOMIC_ACQUIRE, "agent");
        unsigned ok = 1u;
        for (int i2 = 0; i2 < 8; ++i2)
            ok &= (__hip_atomic_load(&ctr[i2 * 32], __ATOMIC_RELAXED, __HIP_MEMORY_SCOPE_AGENT) == 32u) ? 1u : 0u;
        shm[0] = r; shm[1] = ok; shm[2] = x;
    }
    __syncthreads();
    const unsigned rank  = shm[0];
    const unsigned okf   = shm[1];
    const unsigned myxcd = shm[2];
    __syncthreads();

    const int pbm = (int)myxcd * 4 + (int)(rank >> 3);   // persistent row group
    const float C1 = 0.97f;
    const float C2 = (float)(1.0 - 0.97);
    const size_t SBUF = (size_t)32 * 9 * 128 * 25;

    for (int s = 0; s < NSTEPS; ++s) {
        // -------- step boundary: drain + release own group's step s-1 --------
        if (s > 0) {
            asm volatile("s_waitcnt vmcnt(0) lgkmcnt(0)" ::: "memory");
            __syncthreads();
            if (okf) {
                if (tid == 0)
                    __hip_atomic_fetch_add(&ctr[(8192 + (s - 1) * 32 + pbm) * 16], 1u,
                                           __ATOMIC_RELEASE, __HIP_MEMORY_SCOPE_AGENT);
            } else {
                if (tid == 0) {
                    unsigned* slot = &ctr[(1024 + 2048 + (s - 1)) * 32];
                    __hip_atomic_fetch_add(slot, 1u, __ATOMIC_RELEASE, __HIP_MEMORY_SCOPE_AGENT);
                    while (__hip_atomic_load(slot, __ATOMIC_RELAXED, __HIP_MEMORY_SCOPE_AGENT) < 256u)
                        __builtin_amdgcn_s_sleep(4);
                }
                __syncthreads();
                __builtin_amdgcn_fence(__ATOMIC_ACQUIRE, "agent");
            }
        }

        // -------- decode step --------
        const _Float16* A; const _Float16* B; const float* bias;
        int K, mode, rshift = 0, rbuf = 0, wbuf = 0;
        if (s == 0) {
            A = xh; B = fc1h; bias = fc1_b; K = 512; mode = 0;
            rshift = 25; wbuf = 0;
        } else if (s == NSTEPS - 1) {
            A = rb; B = fc2h; bias = fc2_b; K = HID; mode = 3;
        } else {
            const int d = (s - 1) >> 1;
            if (s & 1) {
                A = rb; B = W1h + (size_t)d * HID * HID; bias = b1 + d * HID;
                K = HID; mode = 1;
            } else {
                A = ab; B = W2h + (size_t)d * HID * HID; bias = b2 + d * HID;
                K = HID; mode = 2;
                rbuf = d & 1; wbuf = 1 - rbuf;
                rshift = (d == DEPTH - 1) ? 0 : 25;
            }
        }

        int bm, bn; bool active = true;
        if (okf) {
            if (mode == 3) {
                if (rank < 16u) { bm = (int)myxcd * 4 + (int)(rank >> 2); bn = (int)(rank & 3u); }
                else { active = false; bm = 0; bn = 0; }
            } else {
                bm = pbm; bn = (int)(rank & 7u);
            }
        } else {
            const int b0  = blockIdx.x;
            const int bid = (b0 & 7) * 32 + (b0 >> 3);
            if (mode == 3) {
                if (bid < 128) { bm = bid >> 2; bn = bid & 3; }
                else { active = false; bm = 0; bn = 0; }
            } else {
                bm = bid >> 3; bn = bid & 7;
            }
        }
        if (!active) continue;   // only possible at the final step

        // -------- GEMM core --------
        floatx4 acc[4][2];
        const floatx4 zero = {0.f, 0.f, 0.f, 0.f};
        #pragma unroll
        for (int i = 0; i < 4; ++i)
            #pragma unroll
            for (int j = 0; j < 2; ++j) acc[i][j] = zero;

        auto stageB = [&](int buf, int kt) {
            #pragma unroll
            for (int q = 0; q < 2; ++q) {
                const int c   = w * 2 + q;
                const int row = c * 8 + lr;
                const int jch = lj ^ (row & 7);
                gload_lds16_w((const void*)(B + (size_t)(bn * 128 + row) * K + kt * 64 + jch * 8),
                              (void*)((char*)Bs[buf] + c * 1024));
            }
        };
        auto stageA = [&](int buf, int kt) {
            #pragma unroll
            for (int q = 0; q < 2; ++q) {
                const int c   = w * 2 + q;
                const int row = c * 8 + lr;
                const int jch = lj ^ (row & 7);
                gload_lds16_a((const void*)(A + (size_t)(bm * 128 + row) * K + kt * 64 + jch * 8),
                              (void*)((char*)As[buf] + c * 1024));
            }
        };
        auto stage = [&](int buf, int kt) { stageB(buf, kt); stageA(buf, kt); };

        auto compute = [&](int buf) {
            #pragma unroll
            for (int kk = 0; kk < 2; ++kk) {
                half8 af[4], bf[2];
                #pragma unroll
                for (int fi = 0; fi < 4; ++fi) {
                    const int off = ((wm * 64 + fi * 16 + (l & 15)) * 128 + kk * 64 + ((l >> 4) << 4)) ^ sw;
                    af[fi] = *(const half8*)((const char*)As[buf] + off);
                }
                #pragma unroll
                for (int fj = 0; fj < 2; ++fj) {
                    const int off = ((wn * 32 + fj * 16 + (l & 15)) * 128 + kk * 64 + ((l >> 4) << 4)) ^ sw;
                    bf[fj] = *(const half8*)((const char*)Bs[buf] + off);
                }
                __builtin_amdgcn_s_setprio(1);
                #pragma unroll
                for (int fi = 0; fi < 4; ++fi)
                    #pragma unroll
                    for (int fj = 0; fj < 2; ++fj)
                        acc[fi][fj] = __builtin_amdgcn_mfma_f32_16x16x32_f16(af[fi], bf[fj], acc[fi][fj], 0, 0, 0);
                __builtin_amdgcn_s_setprio(0);
            }
        };

        const int nkt = K >> 6;
        const bool pro = okf && (s > 0);
        if (pro) {
            // weights first (no dependency) — HBM latency hides under the spin
            stageB(0, 0);
            stageB(1, 1);
            if (tid == 0) {
                unsigned* slot = &ctr[(8192 + (s - 1) * 32 + bm) * 16];
                while (__hip_atomic_load(slot, __ATOMIC_RELAXED, __HIP_MEMORY_SCOPE_AGENT) < 8u)
                    __builtin_amdgcn_s_sleep(1);
            }
            __syncthreads();
            stageA(0, 0);
            stageA(1, 1);
        } else {
            stage(0, 0);
            stage(1, 1);
        }

        int cur = 0;
        for (int kt = 0; kt < nkt; ++kt) {
            if (kt + 2 < nkt) {
                int n2 = cur + 2; if (n2 >= 3) n2 -= 3;
                stage(n2, kt + 2);
            }
            const int rem   = nkt - 1 - kt;
            const int ahead = rem < 2 ? rem : 2;
            if (ahead == 2) {
                if (pro && kt == 0) asm volatile("s_waitcnt vmcnt(6)" ::: "memory");
                else                asm volatile("s_waitcnt vmcnt(8)" ::: "memory");
            }
            else if (ahead == 1) asm volatile("s_waitcnt vmcnt(4)" ::: "memory");
            else                 asm volatile("s_waitcnt vmcnt(0)" ::: "memory");
            __builtin_amdgcn_s_barrier();
            __builtin_amdgcn_sched_barrier(0);
            compute(cur);
            __builtin_amdgcn_s_barrier();
            cur = (cur + 1 == 3) ? 0 : cur + 1;
        }

        // -------- epilogue (R9-identical) --------
        const int colb = bn * 128 + wn * 32 + (l & 15);
        const int rowb = bm * 128 + wm * 64 + ((l >> 4) << 2);
        const int jl0  = wn * 32 + (l & 15);
        const int il0  = wm * 64 + ((l >> 4) << 2);

        if (mode == 1) {
            #pragma unroll
            for (int fi = 0; fi < 4; ++fi)
                #pragma unroll
                for (int fj = 0; fj < 2; ++fj) {
                    const int j = colb + fj * 16;
                    const float bj = bias[j];
                    #pragma unroll
                    for (int v = 0; v < 4; ++v)
                        ab[(size_t)(rowb + fi * 16 + v) * HID + j] = (_Float16)fmaxf(acc[fi][fj][v] + bj, 0.f);
                }
        } else if (mode == 3) {
            #pragma unroll
            for (int fi = 0; fi < 4; ++fi)
                #pragma unroll
                for (int fj = 0; fj < 2; ++fj) {
                    const int j = colb + fj * 16;
                    const float bj = bias[j];
                    #pragma unroll
                    for (int v = 0; v < 4; ++v)
                        outp[(size_t)(rowb + fi * 16 + v) * 512 + j] = acc[fi][fj][v] + bj;
                }
        } else {
            float rv[4][2][4];
            if (mode == 2) {
                const float* Srd = Sst + (size_t)rbuf * SBUF + ((size_t)(bm * 9 + bn) * 128) * 25;
                #pragma unroll
                for (int fi = 0; fi < 4; ++fi)
                    #pragma unroll
                    for (int fj = 0; fj < 2; ++fj) {
                        const int jl = jl0 + fj * 16;
                        #pragma unroll
                        for (int v = 0; v < 4; ++v) {
                            const int il = il0 + fi * 16 + v;
                            if (jl >= 25)      rv[fi][fj][v] = Ht[il * 128 + (jl - 25)];
                            else if (bn > 0)   rv[fi][fj][v] = ld_sc0_f32(Srd + il * 25 + jl);
                            else               rv[fi][fj][v] = 0.f;
                        }
                    }
                __syncthreads();   // all Ht reads done before any Ht writes
            }
            float* Swr = Sst + (size_t)wbuf * SBUF + ((size_t)(bm * 9 + bn + 1) * 128) * 25;
            #pragma unroll
            for (int fi = 0; fi < 4; ++fi)
                #pragma unroll
                for (int fj = 0; fj < 2; ++fj) {
                    const int j  = colb + fj * 16;
                    const int jl = jl0 + fj * 16;
                    const float bj = bias[j];
                    #pragma unroll
                    for (int v = 0; v < 4; ++v) {
                        const int i  = rowb + fi * 16 + v;
                        const int il = il0 + fi * 16 + v;
                        const float val = acc[fi][fj][v] + bj;
                        const float hv = (mode == 2) ? (C1 * rv[fi][fj][v] + C2 * val) : val;
                        Ht[il * 128 + jl] = hv;
                        if (rshift == 0) {
                            rb[(size_t)i * HID + j] = (_Float16)hv;
                        } else {
                            const int jd = j + 25;
                            if (jd < HID) rb[(size_t)i * HID + jd] = (_Float16)hv;
                            if (j < 25)   rb[(size_t)i * HID + j]  = (_Float16)0.f;
                            if (jl >= 103) Swr[il * 25 + (jl - 103)] = hv;
                        }
                    }
                }
        }
    }
}

__global__ void cvt_kernel(const float* __restrict__ in, _Float16* __restrict__ out, long n8)
{
    const long stride = (long)gridDim.x * 256;
    for (long idx = (long)blockIdx.x * 256 + threadIdx.x; idx < n8; idx += stride) {
        const floatx4 f0 = ((const floatx4*)in)[idx * 2];
        const floatx4 f1 = ((const floatx4*)in)[idx * 2 + 1];
        half8 h;
        #pragma unroll
        for (int i = 0; i < 4; ++i) {
            h[i]     = (_Float16)f0[i];
            h[4 + i] = (_Float16)f1[i];
        }
        ((half8*)out)[idx] = h;
    }
}

__global__ void zero_ctr(unsigned* __restrict__ ctr, int n)
{
    const int i = blockIdx.x * 256 + threadIdx.x;
    if (i < n) ctr[i] = 0u;
}

static inline void launch_cvt(const float* in, _Float16* out, long n, hipStream_t s)
{
    const long n8 = n / 8;
    int blocks = (int)((n8 + 255) / 256);
    if (blocks > 2048) blocks = 2048;
    cvt_kernel<<<dim3(blocks), dim3(256), 0, s>>>(in, out, n8);
}

extern "C" void kernel_launch(void* const* d_in, const int* in_sizes, int n_in,
                              void* d_out, int out_size, void* d_ws, size_t ws_size,
                              hipStream_t stream)
{
    (void)in_sizes; (void)n_in; (void)out_size; (void)ws_size;
    const float* x     = (const float*)d_in[0];
    const float* fc1_w = (const float*)d_in[1];
    const float* fc1_b = (const float*)d_in[2];
    const float* W1    = (const float*)d_in[3];
    const float* b1    = (const float*)d_in[4];
    const float* W2    = (const float*)d_in[5];
    const float* b2    = (const float*)d_in[6];
    const float* fc2_w = (const float*)d_in[7];
    const float* fc2_b = (const float*)d_in[8];
    float* out = (float*)d_out;

    char* ws = (char*)d_ws;
    _Float16* xh   = (_Float16*)(ws);                    // 4 MiB  [4096][512]
    _Float16* rb   = (_Float16*)(ws + (4ull   << 20));   // 8 MiB  [4096][1024]
    _Float16* ab   = (_Float16*)(ws + (12ull  << 20));   // 8 MiB  [4096][1024]
    _Float16* fc1h = (_Float16*)(ws + (52ull  << 20));   // 1 MiB
    _Float16* fc2h = (_Float16*)(ws + (53ull  << 20));   // 1 MiB
    _Float16* W1h  = (_Float16*)(ws + (54ull  << 20));   // 200 MiB
    _Float16* W2h  = (_Float16*)(ws + (254ull << 20));   // 200 MiB
    unsigned* ctr  = (unsigned*)(ws + (460ull << 20));   // counters + dataflow flags (~1 MiB)
    float*    Sst  = (float*)   (ws + (462ull << 20));   // strip dbuf ~7.4 MiB

    launch_cvt(x, xh, (long)MROWS * 512, stream);
    launch_cvt(fc1_w, fc1h, (long)HID * 512, stream);
    launch_cvt(W1,    W1h,  (long)DEPTH * HID * HID, stream);
    launch_cvt(W2,    W2h,  (long)DEPTH * HID * HID, stream);
    launch_cvt(fc2_w, fc2h, (long)512 * HID, stream);
    zero_ctr<<<dim3(1024), dim3(256), 0, stream>>>(ctr, 262144);

    resnet_persist<<<dim3(256), dim3(512), 0, stream>>>(
        xh, fc1h, fc1_b, W1h, b1, W2h, b2, fc2h, fc2_b,
        Sst, rb, ab, out, ctr);
}

// Round 12
// 4956.337 us; speedup vs baseline: 1.3360x; 1.3360x over previous
//
#include <hip/hip_runtime.h>
#include <cstdint>
#include <cstddef>

#define DEPTH 100
#define HID 1024
#define MROWS 4096
#define NSTEPS 202

typedef _Float16 half8 __attribute__((ext_vector_type(8)));
typedef float floatx4 __attribute__((ext_vector_type(4)));
typedef unsigned uintx4 __attribute__((ext_vector_type(4)));

// B (weights): DMA path, nt = evict-first
__device__ __forceinline__ void gload_lds16_w(const void* g, void* l) {
    __builtin_amdgcn_global_load_lds((const __attribute__((address_space(1))) void*)g,
                                     (__attribute__((address_space(3))) void*)l, 16, 0, 2);
}
// A (activations): VMEM-return path, sc0 = L1-bypass (written by other CUs last step)
__device__ __forceinline__ uintx4 gload16_sc0(const void* p) {
    uintx4 r;
    asm volatile("global_load_dwordx4 %0, %1, off sc0" : "=v"(r) : "v"(p) : "memory");
    return r;
}
__device__ __forceinline__ float ld_sc0_f32(const float* p) {
    return __hip_atomic_load(p, __ATOMIC_RELAXED, __HIP_MEMORY_SCOPE_AGENT);
}

// ============================================================================
// R12 = R9 with the staging split across两 hardware paths:
//   B (weights) stays on global_load_lds DMA (3-deep, counted vmcnt);
//   A (activations) moves to VMEM-return: asm global_load_dwordx4 sc0 -> regs
//   -> swizzled ds_write_b128 into a 2-deep LDS buffer (HK reg-staged pattern).
// DMA bytes per k-tile halve (32->16KB); A flows through L1/L2 in parallel.
// vmcnt ledger (all VMEM manual): entering tile kt outstanding =
//   {B(kt)[2], A(kt+1)[2], B(kt+1)[2]} -> wait vmcnt(4); before dsw: vmcnt(2)
//   (retires A(kt+1), keeps B(kt+1) in flight); lgkmcnt(0) before post-barrier.
// LDS: Adb 2x16K + Bs 3x16K + Ht 64K = 144KB (1 blk/CU, safe margin).
// Everything else byte-identical R9 (best verified: 4920us persist).
// ============================================================================
__global__ __launch_bounds__(512, 1)
void resnet_persist(const _Float16* __restrict__ xh, const _Float16* __restrict__ fc1h,
                    const float* __restrict__ fc1_b,
                    const _Float16* __restrict__ W1h, const float* __restrict__ b1,
                    const _Float16* __restrict__ W2h, const float* __restrict__ b2,
                    const _Float16* __restrict__ fc2h, const float* __restrict__ fc2_b,
                    float* __restrict__ Sst, _Float16* __restrict__ rb,
                    _Float16* __restrict__ ab, float* __restrict__ outp,
                    unsigned* __restrict__ ctr)
{
    __shared__ _Float16 Adb[2][128 * 64];  // 32 KB (reg-staged A, 2-deep)
    __shared__ _Float16 Bs[3][128 * 64];   // 48 KB (DMA B, 3-deep)
    __shared__ float    Ht[128 * 128];     // 64 KB persistent h tile

    const int tid = threadIdx.x;
    const int l   = tid & 63;
    const int w   = tid >> 6;        // wave 0..7
    const int wm  = w >> 2;          // 0..1 along M
    const int wn  = w & 3;           // 0..3 along N

    const int lr = l >> 3;           // row within 8-row staging chunk
    const int lj = l & 7;            // 16B column slot
    const int sw = (l & 7) << 4;     // fragment-read swizzle

    // ---- registration: physical XCD id + rank; verify 32 blocks per XCD ----
    unsigned xcd_s;
    asm volatile("s_getreg_b32 %0, hwreg(HW_REG_XCC_ID)" : "=s"(xcd_s));
    unsigned* shm = (unsigned*)Ht;   // Ht not yet live
    if (tid == 0) {
        const unsigned x = xcd_s & 7u;
        const unsigned r = __hip_atomic_fetch_add(&ctr[x * 32], 1u, __ATOMIC_RELAXED, __HIP_MEMORY_SCOPE_AGENT);
        __hip_atomic_fetch_add(&ctr[8 * 32], 1u, __ATOMIC_RELEASE, __HIP_MEMORY_SCOPE_AGENT);
        while (__hip_atomic_load(&ctr[8 * 32], __ATOMIC_RELAXED, __HIP_MEMORY_SCOPE_AGENT) < 256u)
            __builtin_amdgcn_s_sleep(2);
        __builtin_amdgcn_fence(__ATOMIC_ACQUIRE, "agent");
        unsigned ok = 1u;
        for (int i2 = 0; i2 < 8; ++i2)
            ok &= (__hip_atomic_load(&ctr[i2 * 32], __ATOMIC_RELAXED, __HIP_MEMORY_SCOPE_AGENT) == 32u) ? 1u : 0u;
        shm[0] = r; shm[1] = ok; shm[2] = x;
    }
    __syncthreads();
    const unsigned rank  = shm[0];
    const unsigned okf   = shm[1];
    const unsigned myxcd = shm[2];
    __syncthreads();

    const float C1 = 0.97f;
    const float C2 = (float)(1.0 - 0.97);
    const size_t SBUF = (size_t)32 * 9 * 128 * 25;

    // ds_write dest byte offsets (fixed per thread; swizzled: slot = lj ^ lr)
    const int dd0 = (w * 2 + 0) * 1024 + lr * 128 + ((lj ^ lr) << 4);
    const int dd1 = (w * 2 + 1) * 1024 + lr * 128 + ((lj ^ lr) << 4);

    for (int s = 0; s < NSTEPS; ++s) {
        // -------- inter-step barrier (R9-proven) --------
        if (s > 0) {
            asm volatile("s_waitcnt vmcnt(0) lgkmcnt(0)" ::: "memory");
            __syncthreads();
            if (okf) {
                if (tid == 0) {
                    unsigned* slot = &ctr[(1024 + ((s - 1) * 8 + (int)myxcd)) * 32];
                    __hip_atomic_fetch_add(slot, 1u, __ATOMIC_RELAXED, __HIP_MEMORY_SCOPE_AGENT);
                    while (__hip_atomic_load(slot, __ATOMIC_RELAXED, __HIP_MEMORY_SCOPE_AGENT) < 32u)
                        __builtin_amdgcn_s_sleep(2);
                }
                __syncthreads();
            } else {
                if (tid == 0) {
                    unsigned* slot = &ctr[(1024 + 2048 + (s - 1)) * 32];
                    __hip_atomic_fetch_add(slot, 1u, __ATOMIC_RELEASE, __HIP_MEMORY_SCOPE_AGENT);
                    while (__hip_atomic_load(slot, __ATOMIC_RELAXED, __HIP_MEMORY_SCOPE_AGENT) < 256u)
                        __builtin_amdgcn_s_sleep(4);
                }
                __syncthreads();
                __builtin_amdgcn_fence(__ATOMIC_ACQUIRE, "agent");
            }
            __builtin_amdgcn_sched_barrier(0);
        }

        // -------- decode step --------
        const _Float16* A; const _Float16* B; const float* bias;
        int K, mode, rshift = 0, rbuf = 0, wbuf = 0;
        if (s == 0) {
            A = xh; B = fc1h; bias = fc1_b; K = 512; mode = 0;
            rshift = 25; wbuf = 0;
        } else if (s == NSTEPS - 1) {
            A = rb; B = fc2h; bias = fc2_b; K = HID; mode = 3;
        } else {
            const int d = (s - 1) >> 1;
            if (s & 1) {
                A = rb; B = W1h + (size_t)d * HID * HID; bias = b1 + d * HID;
                K = HID; mode = 1;
            } else {
                A = ab; B = W2h + (size_t)d * HID * HID; bias = b2 + d * HID;
                K = HID; mode = 2;
                rbuf = d & 1; wbuf = 1 - rbuf;
                rshift = (d == DEPTH - 1) ? 0 : 25;
            }
        }

        int bm, bn; bool active = true;
        if (okf) {
            if (mode == 3) {
                if (rank < 16u) { bm = (int)myxcd * 4 + (int)(rank >> 2); bn = (int)(rank & 3u); }
                else { active = false; bm = 0; bn = 0; }
            } else {
                bm = (int)myxcd * 4 + (int)(rank >> 3); bn = (int)(rank & 7u);
            }
        } else {
            const int b0  = blockIdx.x;
            const int bid = (b0 & 7) * 32 + (b0 >> 3);
            if (mode == 3) {
                if (bid < 128) { bm = bid >> 2; bn = bid & 3; }
                else { active = false; bm = 0; bn = 0; }
            } else {
                bm = bid >> 3; bn = bid & 7;
            }
        }
        if (!active) continue;   // only possible at the final step

        // -------- GEMM core --------
        floatx4 acc[4][2];
        const floatx4 zero = {0.f, 0.f, 0.f, 0.f};
        #pragma unroll
        for (int i = 0; i < 4; ++i)
            #pragma unroll
            for (int j = 0; j < 2; ++j) acc[i][j] = zero;

        // A source lane pointers (linear, coalesced 16B/lane)
        const char* a0p = (const char*)A +
            2 * ((size_t)(bm * 128 + (w * 2 + 0) * 8 + lr) * K + lj * 8);
        const char* a1p = (const char*)A +
            2 * ((size_t)(bm * 128 + (w * 2 + 1) * 8 + lr) * K + lj * 8);

        auto stageB = [&](int buf, int kt) {
            #pragma unroll
            for (int q = 0; q < 2; ++q) {
                const int c   = w * 2 + q;
                const int row = c * 8 + lr;
                const int jch = lj ^ (row & 7);
                gload_lds16_w((const void*)(B + (size_t)(bn * 128 + row) * K + kt * 64 + jch * 8),
                              (void*)((char*)Bs[buf] + c * 1024));
            }
        };

        auto compute = [&](int abuf, int buf) {
            #pragma unroll
            for (int kk = 0; kk < 2; ++kk) {
                half8 af[4], bf[2];
                #pragma unroll
                for (int fi = 0; fi < 4; ++fi) {
                    const int off = ((wm * 64 + fi * 16 + (l & 15)) * 128 + kk * 64 + ((l >> 4) << 4)) ^ sw;
                    af[fi] = *(const half8*)((const char*)Adb[abuf] + off);
                }
                #pragma unroll
                for (int fj = 0; fj < 2; ++fj) {
                    const int off = ((wn * 32 + fj * 16 + (l & 15)) * 128 + kk * 64 + ((l >> 4) << 4)) ^ sw;
                    bf[fj] = *(const half8*)((const char*)Bs[buf] + off);
                }
                __builtin_amdgcn_s_setprio(1);
                #pragma unroll
                for (int fi = 0; fi < 4; ++fi)
                    #pragma unroll
                    for (int fj = 0; fj < 2; ++fj)
                        acc[fi][fj] = __builtin_amdgcn_mfma_f32_16x16x32_f16(af[fi], bf[fj], acc[fi][fj], 0, 0, 0);
                __builtin_amdgcn_s_setprio(0);
            }
        };

        const int nkt = K >> 6;
        uintx4 aR0, aR1;

        // ---- prologue: A(0) regs->LDS, B(0), A(1)->regs, B(1) ----
        aR0 = gload16_sc0((const void*)a0p);
        aR1 = gload16_sc0((const void*)a1p);
        asm volatile("s_waitcnt vmcnt(0)" ::: "memory");
        *(uintx4*)((char*)Adb[0] + dd0) = aR0;
        *(uintx4*)((char*)Adb[0] + dd1) = aR1;
        stageB(0, 0);
        aR0 = gload16_sc0((const void*)(a0p + 128));
        aR1 = gload16_sc0((const void*)(a1p + 128));
        stageB(1, 1);
        asm volatile("s_waitcnt lgkmcnt(0)" ::: "memory");
        // outstanding now (old->new): B(0)[2], A(1)[2], B(1)[2]

        int cur = 0;
        for (int kt = 0; kt < nkt; ++kt) {
            // a) retire B(kt); keep A(kt+1), B(kt+1) in flight
            if (kt + 1 < nkt) asm volatile("s_waitcnt vmcnt(4)" ::: "memory");
            else              asm volatile("s_waitcnt vmcnt(0)" ::: "memory");
            __builtin_amdgcn_s_barrier();
            __builtin_amdgcn_sched_barrier(0);
            // d) write A(kt+1) into LDS (retire its loads; B(kt+1) stays in flight)
            if (kt + 1 < nkt) {
                asm volatile("s_waitcnt vmcnt(2)" ::: "memory");
                const int ab2 = (kt + 1) & 1;
                *(uintx4*)((char*)Adb[ab2] + dd0) = aR0;
                *(uintx4*)((char*)Adb[ab2] + dd1) = aR1;
            }
            // e,f) issue A(kt+2) loads + B(kt+2) DMA
            if (kt + 2 < nkt) {
                aR0 = gload16_sc0((const void*)(a0p + (size_t)(kt + 2) * 128));
                aR1 = gload16_sc0((const void*)(a1p + (size_t)(kt + 2) * 128));
                int n2 = cur + 2; if (n2 >= 3) n2 -= 3;
                stageB(n2, kt + 2);
            }
            // g) compute
            compute(kt & 1, cur);
            asm volatile("s_waitcnt lgkmcnt(0)" ::: "memory");
            __builtin_amdgcn_s_barrier();
            cur = (cur + 1 == 3) ? 0 : cur + 1;
        }

        // -------- epilogue (R9-identical) --------
        const int colb = bn * 128 + wn * 32 + (l & 15);
        const int rowb = bm * 128 + wm * 64 + ((l >> 4) << 2);
        const int jl0  = wn * 32 + (l & 15);
        const int il0  = wm * 64 + ((l >> 4) << 2);

        if (mode == 1) {
            #pragma unroll
            for (int fi = 0; fi < 4; ++fi)
                #pragma unroll
                for (int fj = 0; fj < 2; ++fj) {
                    const int j = colb + fj * 16;
                    const float bj = bias[j];
                    #pragma unroll
                    for (int v = 0; v < 4; ++v)
                        ab[(size_t)(rowb + fi * 16 + v) * HID + j] = (_Float16)fmaxf(acc[fi][fj][v] + bj, 0.f);
                }
        } else if (mode == 3) {
            #pragma unroll
            for (int fi = 0; fi < 4; ++fi)
                #pragma unroll
                for (int fj = 0; fj < 2; ++fj) {
                    const int j = colb + fj * 16;
                    const float bj = bias[j];
                    #pragma unroll
                    for (int v = 0; v < 4; ++v)
                        outp[(size_t)(rowb + fi * 16 + v) * 512 + j] = acc[fi][fj][v] + bj;
                }
        } else {
            float rv[4][2][4];
            if (mode == 2) {
                const float* Srd = Sst + (size_t)rbuf * SBUF + ((size_t)(bm * 9 + bn) * 128) * 25;
                #pragma unroll
                for (int fi = 0; fi < 4; ++fi)
                    #pragma unroll
                    for (int fj = 0; fj < 2; ++fj) {
                        const int jl = jl0 + fj * 16;
                        #pragma unroll
                        for (int v = 0; v < 4; ++v) {
                            const int il = il0 + fi * 16 + v;
                            if (jl >= 25)      rv[fi][fj][v] = Ht[il * 128 + (jl - 25)];
                            else if (bn > 0)   rv[fi][fj][v] = ld_sc0_f32(Srd + il * 25 + jl);
                            else               rv[fi][fj][v] = 0.f;
                        }
                    }
                __syncthreads();   // all Ht reads done before any Ht writes
            }
            float* Swr = Sst + (size_t)wbuf * SBUF + ((size_t)(bm * 9 + bn + 1) * 128) * 25;
            #pragma unroll
            for (int fi = 0; fi < 4; ++fi)
                #pragma unroll
                for (int fj = 0; fj < 2; ++fj) {
                    const int j  = colb + fj * 16;
                    const int jl = jl0 + fj * 16;
                    const float bj = bias[j];
                    #pragma unroll
                    for (int v = 0; v < 4; ++v) {
                        const int i  = rowb + fi * 16 + v;
                        const int il = il0 + fi * 16 + v;
                        const float val = acc[fi][fj][v] + bj;
                        const float hv = (mode == 2) ? (C1 * rv[fi][fj][v] + C2 * val) : val;
                        Ht[il * 128 + jl] = hv;
                        if (rshift == 0) {
                            rb[(size_t)i * HID + j] = (_Float16)hv;
                        } else {
                            const int jd = j + 25;
                            if (jd < HID) rb[(size_t)i * HID + jd] = (_Float16)hv;
                            if (j < 25)   rb[(size_t)i * HID + j]  = (_Float16)0.f;
                            if (jl >= 103) Swr[il * 25 + (jl - 103)] = hv;
                        }
                    }
                }
        }
    }
}

__global__ void cvt_kernel(const float* __restrict__ in, _Float16* __restrict__ out, long n8)
{
    const long stride = (long)gridDim.x * 256;
    for (long idx = (long)blockIdx.x * 256 + threadIdx.x; idx < n8; idx += stride) {
        const floatx4 f0 = ((const floatx4*)in)[idx * 2];
        const floatx4 f1 = ((const floatx4*)in)[idx * 2 + 1];
        half8 h;
        #pragma unroll
        for (int i = 0; i < 4; ++i) {
            h[i]     = (_Float16)f0[i];
            h[4 + i] = (_Float16)f1[i];
        }
        ((half8*)out)[idx] = h;
    }
}

__global__ void zero_ctr(unsigned* __restrict__ ctr, int n)
{
    const int i = blockIdx.x * 256 + threadIdx.x;
    if (i < n) ctr[i] = 0u;
}

static inline void launch_cvt(const float* in, _Float16* out, long n, hipStream_t s)
{
    const long n8 = n / 8;
    int blocks = (int)((n8 + 255) / 256);
    if (blocks > 2048) blocks = 2048;
    cvt_kernel<<<dim3(blocks), dim3(256), 0, s>>>(in, out, n8);
}

extern "C" void kernel_launch(void* const* d_in, const int* in_sizes, int n_in,
                              void* d_out, int out_size, void* d_ws, size_t ws_size,
                              hipStream_t stream)
{
    (void)in_sizes; (void)n_in; (void)out_size; (void)ws_size;
    const float* x     = (const float*)d_in[0];
    const float* fc1_w = (const float*)d_in[1];
    const float* fc1_b = (const float*)d_in[2];
    const float* W1    = (const float*)d_in[3];
    const float* b1    = (const float*)d_in[4];
    const float* W2    = (const float*)d_in[5];
    const float* b2    = (const float*)d_in[6];
    const float* fc2_w = (const float*)d_in[7];
    const float* fc2_b = (const float*)d_in[8];
    float* out = (float*)d_out;

    char* ws = (char*)d_ws;
    _Float16* xh   = (_Float16*)(ws);                    // 4 MiB  [4096][512]
    _Float16* rb   = (_Float16*)(ws + (4ull   << 20));   // 8 MiB  [4096][1024]
    _Float16* ab   = (_Float16*)(ws + (12ull  << 20));   // 8 MiB  [4096][1024]
    _Float16* fc1h = (_Float16*)(ws + (52ull  << 20));   // 1 MiB
    _Float16* fc2h = (_Float16*)(ws + (53ull  << 20));   // 1 MiB
    _Float16* W1h  = (_Float16*)(ws + (54ull  << 20));   // 200 MiB
    _Float16* W2h  = (_Float16*)(ws + (254ull << 20));   // 200 MiB
    unsigned* ctr  = (unsigned*)(ws + (460ull << 20));   // barrier counters (padded)
    float*    Sst  = (float*)   (ws + (462ull << 20));   // strip dbuf ~7.4 MiB

    launch_cvt(x, xh, (long)MROWS * 512, stream);
    launch_cvt(fc1_w, fc1h, (long)HID * 512, stream);
    launch_cvt(W1,    W1h,  (long)DEPTH * HID * HID, stream);
    launch_cvt(W2,    W2h,  (long)DEPTH * HID * HID, stream);
    launch_cvt(fc2_w, fc2h, (long)512 * HID, stream);
    zero_ctr<<<dim3(512), dim3(256), 0, stream>>>(ctr, 131072);

    resnet_persist<<<dim3(256), dim3(512), 0, stream>>>(
        xh, fc1h, fc1_b, W1h, b1, W2h, b2, fc2h, fc2_b,
        Sst, rb, ab, out, ctr);
}